// Round 1
// baseline (366.591 us; speedup 1.0000x reference)
//
#include <hip/hip_runtime.h>
#include <stdint.h>

typedef unsigned short u16;
typedef __attribute__((ext_vector_type(8))) short bf16x8;
typedef __attribute__((ext_vector_type(4))) float f32x4;
typedef __attribute__((ext_vector_type(4))) unsigned int u32x4;
typedef __attribute__((ext_vector_type(4))) unsigned short u16x4;

#define MFMA16(a, b, c) __builtin_amdgcn_mfma_f32_16x16x32_bf16(a, b, c, 0, 0, 0)

__device__ __forceinline__ u16 f2bf(float f) {
  union { float f; uint32_t u; } v; v.f = f;
  uint32_t r = v.u + 0x7FFFu + ((v.u >> 16) & 1u);
  return (u16)(r >> 16);
}

// async global->LDS, 16B per lane. LDS dest is wave-uniform base + lane*16.
__device__ __forceinline__ void gload_lds16(const u16* g, u16* l) {
  __builtin_amdgcn_global_load_lds((const __attribute__((address_space(1))) void*)(g),
                                   (__attribute__((address_space(3))) void*)(l), 16, 0, 0);
}

// ---------------- LayerNorm: fp32 [rows][1024] -> bf16 [rows][1024] ----------------
__global__ __launch_bounds__(256) void ln_kernel(const float* __restrict__ x,
                                                 const float* __restrict__ g,
                                                 const float* __restrict__ beta,
                                                 u16* __restrict__ out) {
  int row = blockIdx.x;
  int tid = threadIdx.x;
  float4 v = ((const float4*)(x + (size_t)row * 1024))[tid];
  float s = v.x + v.y + v.z + v.w;
  float ss = v.x * v.x + v.y * v.y + v.z * v.z + v.w * v.w;
#pragma unroll
  for (int m = 1; m < 64; m <<= 1) { s += __shfl_xor(s, m); ss += __shfl_xor(ss, m); }
  __shared__ float red[8];
  int wave = tid >> 6, lane = tid & 63;
  if (lane == 0) { red[wave] = s; red[4 + wave] = ss; }
  __syncthreads();
  s = red[0] + red[1] + red[2] + red[3];
  ss = red[4] + red[5] + red[6] + red[7];
  float mean = s * (1.0f / 1024.0f);
  float var = ss * (1.0f / 1024.0f) - mean * mean;
  float rstd = rsqrtf(var + 1e-5f);
  float4 gv = ((const float4*)g)[tid];
  float4 bv = ((const float4*)beta)[tid];
  u16x4 o;
  o.x = f2bf((v.x - mean) * rstd * gv.x + bv.x);
  o.y = f2bf((v.y - mean) * rstd * gv.y + bv.y);
  o.z = f2bf((v.z - mean) * rstd * gv.z + bv.z);
  o.w = f2bf((v.w - mean) * rstd * gv.w + bv.w);
  *(u16x4*)(out + (size_t)row * 1024 + tid * 4) = o;
}

// ------------- batched transpose: in fp32 [K][N] -> out bf16 [N][K] -------------
__global__ __launch_bounds__(256) void transpose_f32_bf16(const float* __restrict__ in,
                                                          u16* __restrict__ out,
                                                          int K, int N,
                                                          size_t in_bstride, size_t out_bstride) {
  __shared__ float tile[32][33];
  const float* I = in + (size_t)blockIdx.z * in_bstride;
  u16* O = out + (size_t)blockIdx.z * out_bstride;
  int n0 = blockIdx.x * 32, k0 = blockIdx.y * 32;
  int tx = threadIdx.x & 31, ty = threadIdx.x >> 5;  // ty 0..7
#pragma unroll
  for (int i = 0; i < 4; i++)
    tile[ty + i * 8][tx] = I[(size_t)(k0 + ty + i * 8) * N + n0 + tx];
  __syncthreads();
#pragma unroll
  for (int i = 0; i < 4; i++)
    O[(size_t)(n0 + ty + i * 8) * K + k0 + tx] = f2bf(tile[tx][ty + i * 8]);
}

// ------------------------- GEMM: C[M][N] = A[M][K] * Bt[N][K]^T -------------------------
// 128x128 tile, BK=32, 256 threads = 4 waves (2x2), each wave 64x64 out.
// EP 0: QKV scatter (out0=q, out1=k, out2=vT)
// EP 1: fp32 out = acc + bias + res      (Wo projection + residual)
// EP 2: bf16 out = relu(acc + bias)      (FFN1)
// EP 3: fp32 out = acc + bias + res      (FFN2, res==out buffer)
template <int EP>
__global__ __launch_bounds__(256) void gemm_bt(const u16* __restrict__ A,
                                               const u16* __restrict__ Bt,
                                               int M, int N, int K,
                                               void* __restrict__ out0,
                                               u16* __restrict__ out1,
                                               u16* __restrict__ out2,
                                               const float* __restrict__ bias,
                                               const float* __restrict__ res) {
  __shared__ u16 As[128 * 32];
  __shared__ u16 Bs[128 * 32];
  int tid = threadIdx.x;
  int lane = tid & 63, wave = tid >> 6;
  int wr = wave >> 1, wc = wave & 1;
  int bm0 = blockIdx.y * 128, bn0 = blockIdx.x * 128;
  f32x4 acc[4][4] = {};

  for (int k0 = 0; k0 < K; k0 += 32) {
    __syncthreads();
    {
      int c0 = tid, c1 = tid + 256;
      const u16* gA0 = A + (size_t)(bm0 + (c0 >> 2)) * K + k0 + (c0 & 3) * 8;
      const u16* gA1 = A + (size_t)(bm0 + (c1 >> 2)) * K + k0 + (c1 & 3) * 8;
      const u16* gB0 = Bt + (size_t)(bn0 + (c0 >> 2)) * K + k0 + (c0 & 3) * 8;
      const u16* gB1 = Bt + (size_t)(bn0 + (c1 >> 2)) * K + k0 + (c1 & 3) * 8;
      gload_lds16(gA0, As + wave * 512);
      gload_lds16(gA1, As + 2048 + wave * 512);
      gload_lds16(gB0, Bs + wave * 512);
      gload_lds16(gB1, Bs + 2048 + wave * 512);
    }
    __syncthreads();
    bf16x8 a[4], b[4];
#pragma unroll
    for (int mt = 0; mt < 4; mt++)
      a[mt] = *(const bf16x8*)(As + (wr * 64 + mt * 16 + (lane & 15)) * 32 + (lane >> 4) * 8);
#pragma unroll
    for (int nt = 0; nt < 4; nt++)
      b[nt] = *(const bf16x8*)(Bs + (wc * 64 + nt * 16 + (lane & 15)) * 32 + (lane >> 4) * 8);
#pragma unroll
    for (int mt = 0; mt < 4; mt++)
#pragma unroll
      for (int nt = 0; nt < 4; nt++)
        acc[mt][nt] = MFMA16(a[mt], b[nt], acc[mt][nt]);
  }

#pragma unroll
  for (int mt = 0; mt < 4; mt++) {
#pragma unroll
    for (int nt = 0; nt < 4; nt++) {
#pragma unroll
      for (int j = 0; j < 4; j++) {
        int gr = bm0 + wr * 64 + mt * 16 + (lane >> 4) * 4 + j;
        int gc = bn0 + wc * 64 + nt * 16 + (lane & 15);
        float val = acc[mt][nt][j];
        if constexpr (EP == 0) {
          int b_ = gr >> 11, t_ = gr & 2047;
          int sec = gc >> 10, nn = gc & 1023, h_ = nn >> 6, e_ = nn & 63;
          size_t bh = (size_t)(b_ * 16 + h_);
          if (sec == 0)      ((u16*)out0)[(bh * 2048 + t_) * 64 + e_] = f2bf(val);
          else if (sec == 1) out1[(bh * 2048 + t_) * 64 + e_] = f2bf(val);
          else               out2[(bh * 64 + e_) * 2048 + t_] = f2bf(val);
        } else if constexpr (EP == 1 || EP == 3) {
          ((float*)out0)[(size_t)gr * N + gc] = val + bias[gc] + res[(size_t)gr * N + gc];
        } else if constexpr (EP == 2) {
          float v = val + bias[gc];
          ((u16*)out0)[(size_t)gr * N + gc] = f2bf(fmaxf(v, 0.0f));
        }
      }
    }
  }
}

// ------------------------- causal flash attention -------------------------
// q,k: bf16 [B*H][T][64]; vt: bf16 [B*H][64][T]; o: bf16 [B][T][1024] (head-concat)
// block: 256 thr = 4 waves; 64 Q rows/block (16/wave); KV tiles of 64.
__global__ __launch_bounds__(256) void attn_kernel(const u16* __restrict__ q,
                                                   const u16* __restrict__ k,
                                                   const u16* __restrict__ vt,
                                                   u16* __restrict__ o) {
  __shared__ u16 Ks[64 * 72];   // [s][e], pad to 72
  __shared__ u16 Vs[64 * 72];   // [e][s], pad to 72
  __shared__ u16 Ps[4 * 16 * 72];
  int bh = blockIdx.y;
  int qb0 = blockIdx.x * 64;
  int tid = threadIdx.x, lane = tid & 63, wave = tid >> 6;
  const u16* qbase = q + (size_t)bh * 2048 * 64;
  const u16* kbase = k + (size_t)bh * 2048 * 64;
  const u16* vbase = vt + (size_t)bh * 64 * 2048;

  int qrow_a = qb0 + wave * 16 + (lane & 15);
  bf16x8 qf[2];
  qf[0] = *(const bf16x8*)(qbase + (size_t)qrow_a * 64 + (lane >> 4) * 8);
  qf[1] = *(const bf16x8*)(qbase + (size_t)qrow_a * 64 + 32 + (lane >> 4) * 8);

  float m_r[4], l_r[4];
  f32x4 of[4] = {};
#pragma unroll
  for (int j = 0; j < 4; j++) { m_r[j] = -1e30f; l_r[j] = 0.0f; }
  int qrow_c = qb0 + wave * 16 + (lane >> 4) * 4;

  int nkb = blockIdx.x + 1;
  u16* Pw = Ps + wave * 16 * 72;
  for (int kb = 0; kb < nkb; kb++) {
    __syncthreads();
    // stage K tile [64][64] and V^T tile [64][64]
#pragma unroll
    for (int r = 0; r < 2; r++) {
      int c = tid + r * 256;
      int row = c >> 3, ch = c & 7;
      *(u32x4*)(Ks + row * 72 + ch * 8) =
          *(const u32x4*)(kbase + (size_t)(kb * 64 + row) * 64 + ch * 8);
      *(u32x4*)(Vs + row * 72 + ch * 8) =
          *(const u32x4*)(vbase + (size_t)row * 2048 + kb * 64 + ch * 8);
    }
    __syncthreads();
    // S = Q K^T
    f32x4 s[4] = {};
#pragma unroll
    for (int nt = 0; nt < 4; nt++) {
      bf16x8 kf0 = *(const bf16x8*)(Ks + (nt * 16 + (lane & 15)) * 72 + (lane >> 4) * 8);
      bf16x8 kf1 = *(const bf16x8*)(Ks + (nt * 16 + (lane & 15)) * 72 + 32 + (lane >> 4) * 8);
      s[nt] = MFMA16(qf[0], kf0, s[nt]);
      s[nt] = MFMA16(qf[1], kf1, s[nt]);
    }
    // online softmax (rows live in (lane>>4) groups of 16 lanes)
    float p[4][4];
    float tmax[4] = {-1e30f, -1e30f, -1e30f, -1e30f};
#pragma unroll
    for (int nt = 0; nt < 4; nt++)
#pragma unroll
      for (int j = 0; j < 4; j++) {
        float v = s[nt][j] * 0.03125f;  // scale D^-0.5 = 1/32
        int sc = kb * 64 + nt * 16 + (lane & 15);
        if (sc > qrow_c + j) v = -1e30f;
        p[nt][j] = v;
        tmax[j] = fmaxf(tmax[j], v);
      }
#pragma unroll
    for (int j = 0; j < 4; j++)
#pragma unroll
      for (int msk = 1; msk < 16; msk <<= 1)
        tmax[j] = fmaxf(tmax[j], __shfl_xor(tmax[j], msk));
    float alpha[4], rs[4];
#pragma unroll
    for (int j = 0; j < 4; j++) {
      float mn = fmaxf(m_r[j], tmax[j]);
      alpha[j] = __expf(m_r[j] - mn);
      m_r[j] = mn;
      rs[j] = 0.0f;
    }
#pragma unroll
    for (int nt = 0; nt < 4; nt++)
#pragma unroll
      for (int j = 0; j < 4; j++) {
        float e = __expf(p[nt][j] - m_r[j]);
        p[nt][j] = e;
        rs[j] += e;
      }
#pragma unroll
    for (int j = 0; j < 4; j++) {
#pragma unroll
      for (int msk = 1; msk < 16; msk <<= 1) rs[j] += __shfl_xor(rs[j], msk);
      l_r[j] = l_r[j] * alpha[j] + rs[j];
    }
#pragma unroll
    for (int et = 0; et < 4; et++)
#pragma unroll
      for (int j = 0; j < 4; j++) of[et][j] *= alpha[j];
    // P -> LDS (bf16), reshape to A-fragments
#pragma unroll
    for (int nt = 0; nt < 4; nt++)
#pragma unroll
      for (int j = 0; j < 4; j++)
        Pw[((lane >> 4) * 4 + j) * 72 + nt * 16 + (lane & 15)] = f2bf(p[nt][j]);
    bf16x8 pa0 = *(const bf16x8*)(Pw + (lane & 15) * 72 + (lane >> 4) * 8);
    bf16x8 pa1 = *(const bf16x8*)(Pw + (lane & 15) * 72 + 32 + (lane >> 4) * 8);
#pragma unroll
    for (int et = 0; et < 4; et++) {
      bf16x8 v0 = *(const bf16x8*)(Vs + (et * 16 + (lane & 15)) * 72 + (lane >> 4) * 8);
      bf16x8 v1 = *(const bf16x8*)(Vs + (et * 16 + (lane & 15)) * 72 + 32 + (lane >> 4) * 8);
      of[et] = MFMA16(pa0, v0, of[et]);
      of[et] = MFMA16(pa1, v1, of[et]);
    }
  }
  // write O / l, head-concat layout
  int hh = bh & 15, bb = bh >> 4;
#pragma unroll
  for (int j = 0; j < 4; j++) {
    float inv = 1.0f / l_r[j];
    int trow = qrow_c + j;
#pragma unroll
    for (int et = 0; et < 4; et++) {
      o[((size_t)(bb * 2048 + trow)) * 1024 + hh * 64 + et * 16 + (lane & 15)] =
          f2bf(of[et][j] * inv);
    }
  }
}

extern "C" void kernel_launch(void* const* d_in, const int* in_sizes, int n_in,
                              void* d_out, int out_size, void* d_ws, size_t ws_size,
                              hipStream_t stream) {
  const float* x = (const float*)d_in[0];
  const float* Wq = (const float*)d_in[1];
  const float* Wk = (const float*)d_in[2];
  const float* Wv = (const float*)d_in[3];
  const float* Wo = (const float*)d_in[4];
  const float* bo = (const float*)d_in[5];
  const float* W1 = (const float*)d_in[6];
  const float* b1 = (const float*)d_in[7];
  const float* W2 = (const float*)d_in[8];
  const float* b2 = (const float*)d_in[9];
  const float* g1 = (const float*)d_in[10];
  const float* be1 = (const float*)d_in[11];
  const float* g2 = (const float*)d_in[12];
  const float* be2 = (const float*)d_in[13];
  float* out = (float*)d_out;
  char* ws = (char*)d_ws;
  const size_t MB = 1024ull * 1024ull;

  u16* h = (u16*)(ws + 0);          // ln1 out, later reused as attention out (o)
  u16* o = h;
  u16* BtQKV = (u16*)(ws + 8 * MB);  // 3072x1024 bf16; later reused for WoT
  u16* WoT = BtQKV;
  u16* qb = (u16*)(ws + 14 * MB);
  u16* kb = (u16*)(ws + 22 * MB);
  u16* vtb = (u16*)(ws + 30 * MB);  // later reused as h2
  u16* h2 = vtb;
  u16* W1T = (u16*)(ws + 38 * MB);
  u16* yb = (u16*)(ws + 46 * MB);   // 4096x4096 bf16 (32MB)
  u16* W2T = (u16*)(ws + 14 * MB);  // reuse q/k region

  // 1. LN1: x -> h (bf16)
  ln_kernel<<<4096, 256, 0, stream>>>(x, g1, be1, h);
  // 2. weight transposes for QKV (per-head [1024][64] -> [64][1024])
  transpose_f32_bf16<<<dim3(2, 32, 16), 256, 0, stream>>>(Wq, BtQKV, 1024, 64,
                                                          (size_t)1024 * 64, (size_t)64 * 1024);
  transpose_f32_bf16<<<dim3(2, 32, 16), 256, 0, stream>>>(Wk, BtQKV + 1024 * 1024, 1024, 64,
                                                          (size_t)1024 * 64, (size_t)64 * 1024);
  transpose_f32_bf16<<<dim3(2, 32, 16), 256, 0, stream>>>(Wv, BtQKV + 2048 * 1024, 1024, 64,
                                                          (size_t)1024 * 64, (size_t)64 * 1024);
  // 3. QKV projection: [4096][1024] x [3072][1024]^T, scatter epilogue
  gemm_bt<0><<<dim3(24, 32), 256, 0, stream>>>(h, BtQKV, 4096, 3072, 1024,
                                               (void*)qb, kb, vtb, nullptr, nullptr);
  // 4. causal attention -> o (bf16 [B][T][D])
  attn_kernel<<<dim3(32, 32), 256, 0, stream>>>(qb, kb, vtb, o);
  // 5. Wo transpose
  transpose_f32_bf16<<<dim3(32, 32, 1), 256, 0, stream>>>(Wo, WoT, 1024, 1024, 0, 0);
  // 6. x1 = x + o@Wo + bo  -> d_out (fp32)
  gemm_bt<1><<<dim3(8, 32), 256, 0, stream>>>(o, WoT, 4096, 1024, 1024,
                                              (void*)out, nullptr, nullptr, bo, x);
  // 7. LN2: x1 -> h2 (bf16)
  ln_kernel<<<4096, 256, 0, stream>>>(out, g2, be2, h2);
  // 8. W1 transpose [1024][4096] -> [4096][1024]
  transpose_f32_bf16<<<dim3(128, 32, 1), 256, 0, stream>>>(W1, W1T, 1024, 4096, 0, 0);
  // 9. FFN1: y = relu(h2@W1 + b1) (bf16)
  gemm_bt<2><<<dim3(32, 32), 256, 0, stream>>>(h2, W1T, 4096, 4096, 1024,
                                               (void*)yb, nullptr, nullptr, b1, nullptr);
  // 10. W2 transpose [4096][1024] -> [1024][4096]
  transpose_f32_bf16<<<dim3(32, 128, 1), 256, 0, stream>>>(W2, W2T, 4096, 1024, 0, 0);
  // 11. out = x1 + y@W2 + b2 (fp32, reads+rewrites d_out)
  gemm_bt<3><<<dim3(8, 32), 256, 0, stream>>>(yb, W2T, 4096, 1024, 4096,
                                              (void*)out, nullptr, nullptr, b2, out);
}